// Round 1
// baseline (27.842 us; speedup 1.0000x reference)
//
#include <hip/hip_runtime.h>

// LIF constant-current encoder: events[t, e] = spike of neuron e at step t.
// v' = v + 0.1*((0 - v) + i); i' = i + 0.2*(-i); z = (v' - 1 > 0);
// v <- z ? 0 : v'; i <- i' + x.
// All arithmetic via explicitly-rounded intrinsics to match numpy f32
// mul-then-add exactly (no FMA contraction; spike outputs are 0/1 so a
// 1-ulp divergence near threshold would flip an output and fail absmax).

__global__ __launch_bounds__(256) void CurrentEncode_57286273794981_kernel(
    const float4* __restrict__ in4, float* __restrict__ out,
    int n, int steps) {
  const int gid = blockIdx.x * 256 + threadIdx.x;
  const int n4 = n >> 2;
  if (gid >= n4) return;

  const float4 xin = in4[gid];
  float x[4] = {xin.x, xin.y, xin.z, xin.w};
  float v[4] = {0.0f, 0.0f, 0.0f, 0.0f};
  float c[4] = {0.0f, 0.0f, 0.0f, 0.0f};

  float4* out4 = reinterpret_cast<float4*>(out);
  const int n4row = n4;  // float4s per time-step row

  for (int t = 0; t < steps; ++t) {
    float z[4];
#pragma unroll
    for (int j = 0; j < 4; ++j) {
      // v_decayed = v + 0.1f * ((0 - v) + i)   [numpy f32 order, no FMA]
      float tmp = __fadd_rn(__fsub_rn(0.0f, v[j]), c[j]);
      float vd  = __fadd_rn(v[j], __fmul_rn(0.1f, tmp));
      // i_decayed = i + 0.2f * (-i)
      float id  = __fadd_rn(c[j], __fmul_rn(0.2f, __fsub_rn(0.0f, c[j])));
      // z = (v_decayed - 1.0f > 0)
      bool spike = (__fsub_rn(vd, 1.0f) > 0.0f);
      z[j] = spike ? 1.0f : 0.0f;
      // v_new = z ? V_RESET : v_decayed  (exact: (1-z)*vd + z*0)
      v[j] = spike ? 0.0f : vd;
      // i_new = i_decayed + x
      c[j] = __fadd_rn(id, x[j]);
    }
    out4[(size_t)t * n4row + gid] = make_float4(z[0], z[1], z[2], z[3]);
  }
}

extern "C" void kernel_launch(void* const* d_in, const int* in_sizes, int n_in,
                              void* d_out, int out_size, void* d_ws, size_t ws_size,
                              hipStream_t stream) {
  const float* in = (const float*)d_in[0];
  float* out = (float*)d_out;
  const int n = in_sizes[0];          // 3*640*640 = 1228800 (divisible by 4)
  const int steps = out_size / n;     // 32
  const int n4 = n >> 2;
  const int block = 256;
  const int grid = (n4 + block - 1) / block;  // 1200 blocks
  CurrentEncode_57286273794981_kernel<<<grid, block, 0, stream>>>(
      (const float4*)in, out, n, steps);
}